// Round 3
// baseline (5393.196 us; speedup 1.0000x reference)
//
#include <hip/hip_runtime.h>

#define N_TOK 524288
#define DIM 128
#define NCODE 512
#define TAU 5e-5f

// ws layout: [0,8) double loss_acc | [8,12) int cnt | [16,...) int list[cap]

// numpy-pairwise-style fp32 sum of 128 squares: 8 accumulators stride 8,
// separate mul/add rounding, combined ((r0+r1)+(r2+r3))+((r4+r5)+(r6+r7)).
__device__ __forceinline__ float np_sumsq128(const float* __restrict__ p) {
#pragma clang fp contract(off)
    float r[8];
#pragma unroll
    for (int j = 0; j < 8; ++j) { float v = p[j]; r[j] = v * v; }
#pragma unroll
    for (int i = 8; i < 128; i += 8) {
#pragma unroll
        for (int j = 0; j < 8; ++j) { float v = p[i + j]; r[j] = r[j] + v * v; }
    }
    return ((r[0] + r[1]) + (r[2] + r[3])) + ((r[4] + r[5]) + (r[6] + r[7]));
}

// sgemm-style fp32 dot: sequential FMA chain in natural order.
__device__ __forceinline__ float seq_dot128(const float* __restrict__ a,
                                            const float* __restrict__ b) {
    float acc = 0.f;
#pragma unroll
    for (int d = 0; d < DIM; ++d) acc = __builtin_fmaf(a[d], b[d], acc);
    return acc;
}

// Full numpy-fp32 emulation of argmin over all codes for one token (scalar).
__device__ int np_argmin_token(const float* __restrict__ zrow,
                               const float* __restrict__ emb) {
    float zn = np_sumsq128(zrow);
    float bd = 1e30f; int bk = 0;
    for (int k = 0; k < NCODE; ++k) {
        const float* e = emb + (size_t)k * DIM;
        float en = np_sumsq128(e);
        float dot = seq_dot128(zrow, e);
        float t = zn + en;           // fp32 add (grid ~1.5e-5 at 128)
        float c = t - 2.0f * dot;    // 2*dot exact; single fp32 rounding
        if (c < bd) { bd = c; bk = k; }  // strict < = np first-occurrence
    }
    return bk;
}

__global__ void vq_prep(double* loss_acc, int* cnt) {
    *loss_acc = 0.0;
    *cnt = 0;
}

__global__ __launch_bounds__(256) void vq_main(
    const float* __restrict__ z, const float* __restrict__ emb,
    float* __restrict__ out_q, float* __restrict__ out_idx,
    double* __restrict__ loss_acc, int* __restrict__ cnt,
    int* __restrict__ list, int cap)
{
    __shared__ float s_enorm[NCODE];
    for (int k = threadIdx.x; k < NCODE; k += 256) {
        const float4* ep = (const float4*)(emb + (size_t)k * DIM);
        float s0 = 0.f, s1 = 0.f, s2 = 0.f, s3 = 0.f;
#pragma unroll
        for (int j = 0; j < DIM / 4; ++j) {
            float4 e = ep[j];
            s0 = fmaf(e.x, e.x, s0); s1 = fmaf(e.y, e.y, s1);
            s2 = fmaf(e.z, e.z, s2); s3 = fmaf(e.w, e.w, s3);
        }
        s_enorm[k] = (s0 + s1) + (s2 + s3);
    }
    __syncthreads();

    int n = blockIdx.x * 256 + threadIdx.x;
    const float4* zp = (const float4*)(z + (size_t)n * DIM);
    float4 zr[DIM / 4];
#pragma unroll
    for (int j = 0; j < DIM / 4; ++j) zr[j] = zp[j];

    // fast fine-grained scan: d~ = ||e||^2 - 2 z.e  (||z||^2 dropped)
    float m1 = 1e30f, m2 = 1e30f;
    int best = 0;
    for (int k = 0; k < NCODE; ++k) {
        const float4* ep = (const float4*)(emb + (size_t)k * DIM);  // wave-uniform
        float ax = 0.f, ay = 0.f, az = 0.f, aw = 0.f;
#pragma unroll
        for (int j = 0; j < DIM / 4; ++j) {
            float4 e = ep[j];
            ax = fmaf(zr[j].x, e.x, ax);
            ay = fmaf(zr[j].y, e.y, ay);
            az = fmaf(zr[j].z, e.z, az);
            aw = fmaf(zr[j].w, e.w, aw);
        }
        float dot = (ax + ay) + (az + aw);
        float d = fmaf(-2.0f, dot, s_enorm[k]);
        if (d < m1) { m2 = m1; m1 = d; best = k; }
        else if (d < m2) { m2 = d; }
    }

    // fine gap below the reference's coarse quantization scale -> emulate np fp32
    if (m2 - m1 < TAU) {
        int pos = atomicAdd(cnt, 1);
        if (pos < cap) {
            list[pos] = n;  // refined by vq_refine
        } else {
            best = np_argmin_token(z + (size_t)n * DIM, emb);  // cold fallback
        }
    }

    const float4* eb = (const float4*)(emb + (size_t)best * DIM);
    float4* oq = (float4*)(out_q + (size_t)n * DIM);
    float sx = 0.f, sy = 0.f, szz = 0.f, sw = 0.f;
#pragma unroll
    for (int j = 0; j < DIM / 4; ++j) {
        float4 e = eb[j];
        float4 zz = zr[j];
        float dx = e.x - zz.x, dy = e.y - zz.y, dz = e.z - zz.z, dw = e.w - zz.w;
        float4 o; o.x = zz.x + dx; o.y = zz.y + dy; o.z = zz.z + dz; o.w = zz.w + dw;
        oq[j] = o;
        sx = fmaf(dx, dx, sx); sy = fmaf(dy, dy, sy);
        szz = fmaf(dz, dz, szz); sw = fmaf(dw, dw, sw);
    }
    out_idx[n] = (float)best;

    double sd = (double)((sx + sy) + (szz + sw));
#pragma unroll
    for (int off = 32; off > 0; off >>= 1) sd += __shfl_down(sd, off);
    if ((threadIdx.x & 63) == 0) atomicAdd(loss_acc, sd);
}

// One block per ambiguous token; numpy-fp32 emulated distances; block argmin
// with first-occurrence (lowest k) tie-break.
__global__ __launch_bounds__(256) void vq_refine(
    const float* __restrict__ z, const float* __restrict__ emb,
    float* __restrict__ out_q, float* __restrict__ out_idx,
    const int* __restrict__ cnt, const int* __restrict__ list, int cap)
{
    __shared__ float s_z[DIM];
    __shared__ float s_d[256];
    __shared__ int s_k[256];
    int nwork = *cnt;
    if (nwork > cap) nwork = cap;
    for (int i = blockIdx.x; i < nwork; i += gridDim.x) {
        int n = list[i];
        if (threadIdx.x < DIM) s_z[threadIdx.x] = z[(size_t)n * DIM + threadIdx.x];
        __syncthreads();

        float zn = np_sumsq128(s_z);  // identical across threads (same order)
        float bd = 1e30f; int bk = 1 << 30;
#pragma unroll
        for (int t = 0; t < NCODE / 256; ++t) {
            int k = threadIdx.x + 256 * t;
            const float* e = emb + (size_t)k * DIM;
            float en = np_sumsq128(e);
            float dot = seq_dot128(s_z, e);
            float tt = zn + en;
            float c = tt - 2.0f * dot;
            if (c < bd || (c == bd && k < bk)) { bd = c; bk = k; }
        }
        s_d[threadIdx.x] = bd;
        s_k[threadIdx.x] = bk;
        __syncthreads();
        for (int s = 128; s > 0; s >>= 1) {
            if (threadIdx.x < s) {
                float od = s_d[threadIdx.x + s];
                int ok = s_k[threadIdx.x + s];
                if (od < s_d[threadIdx.x] ||
                    (od == s_d[threadIdx.x] && ok < s_k[threadIdx.x])) {
                    s_d[threadIdx.x] = od;
                    s_k[threadIdx.x] = ok;
                }
            }
            __syncthreads();
        }
        int best = s_k[0];

        if (threadIdx.x < DIM) {
            float e = emb[(size_t)best * DIM + threadIdx.x];
            float zz = s_z[threadIdx.x];
            out_q[(size_t)n * DIM + threadIdx.x] = zz + (e - zz);
        }
        if (threadIdx.x == 0) out_idx[n] = (float)best;
        __syncthreads();
    }
}

__global__ void vq_final(const double* __restrict__ loss_acc, float* __restrict__ out_loss) {
    double m = *loss_acc / ((double)N_TOK * (double)DIM);
    *out_loss = (float)(1.25 * m);  // q_latent + 0.25 * e_latent (equal values)
}

extern "C" void kernel_launch(void* const* d_in, const int* in_sizes, int n_in,
                              void* d_out, int out_size, void* d_ws, size_t ws_size,
                              hipStream_t stream) {
    const float* z = (const float*)d_in[0];
    const float* emb = (const float*)d_in[1];
    float* out_q = (float*)d_out;
    float* out_loss = out_q + (size_t)N_TOK * DIM;
    float* out_idx = out_loss + 1;

    char* ws = (char*)d_ws;
    double* loss_acc = (double*)ws;
    int* cnt = (int*)(ws + 8);
    int* list = (int*)(ws + 16);
    long cap_l = ((long)ws_size - 16) / 4;
    if (cap_l < 0) cap_l = 0;
    if (cap_l > N_TOK) cap_l = N_TOK;
    int cap = (int)cap_l;

    vq_prep<<<1, 1, 0, stream>>>(loss_acc, cnt);
    vq_main<<<N_TOK / 256, 256, 0, stream>>>(z, emb, out_q, out_idx,
                                             loss_acc, cnt, list, cap);
    vq_refine<<<1024, 256, 0, stream>>>(z, emb, out_q, out_idx, cnt, list, cap);
    vq_final<<<1, 1, 0, stream>>>(loss_acc, out_loss);
}